// Round 3
// baseline (198.194 us; speedup 1.0000x reference)
//
#include <hip/hip_runtime.h>
#include <hip/hip_bf16.h>
#include <cstdint>

// Problem constants (match reference)
#define Bn 8
#define Ln 4096
#define Dn 2048
#define Gn 32
#define GSn 64
#define CLn 1024                      // chunk length along L (x-chunk = 64MB, L3-resident)
#define NCH (Ln / CLn)                // 4 chunks
static constexpr float EPS = 1e-5f;

// ---------------------------------------------------------------------------
// P1: per-(b,t,g) group means for one time-chunk. One block per (b,tt) row.
// ---------------------------------------------------------------------------
__global__ __launch_bounds__(256) void k_group_means(const float* __restrict__ x,
                                                     float* __restrict__ m,
                                                     int t_base) {
    const int idx = blockIdx.x;          // 0 .. B*CL-1
    const int b = idx / CLn;
    const int tt = idx - b * CLn;
    const int row = b * Ln + t_base + tt;
    const int tid = threadIdx.x;
    const float4* xr = reinterpret_cast<const float4*>(x + (size_t)row * Dn) + tid * 2;
    float4 a = xr[0];
    float4 c = xr[1];
    float s = (a.x + a.y) + (a.z + a.w) + (c.x + c.y) + (c.z + c.w);
    s += __shfl_xor(s, 1);
    s += __shfl_xor(s, 2);
    s += __shfl_xor(s, 4);
    if ((tid & 7) == 0) {
        const int g = tid >> 3;
        m[(size_t)row * Gn + g] = s * (1.0f / (float)GSn);
    }
}

// ---------------------------------------------------------------------------
// P2: chunked chain scan. One block per (b,g) chain; CL timesteps per chunk,
// closed-form Welford via masked prefix sums, carry (S,Q,P) in ws between
// chunks. Chunk 0 ignores ws (deterministic across replays).
// ---------------------------------------------------------------------------
__global__ __launch_bounds__(256) void k_scan(const float* __restrict__ m,
                                              const int* __restrict__ mask,
                                              const int* __restrict__ prev_count,
                                              const float* __restrict__ prev_mean,
                                              const float* __restrict__ prev_var,
                                              float* __restrict__ mu,
                                              float* __restrict__ rstd,
                                              float* __restrict__ carryS,
                                              float* __restrict__ carryQ,
                                              float* __restrict__ carryP,
                                              float* __restrict__ out_count,
                                              float* __restrict__ out_mean,
                                              float* __restrict__ out_var,
                                              int t_base) {
    const int bg = blockIdx.x;           // b*G + g
    const int b = bg / Gn;
    const int g = bg - b * Gn;
    const int tid = threadIdx.x;
    constexpr int TPT = CLn / 256;       // 4 timesteps per thread
    const int t0 = t_base + tid * TPT;

    // carry from previous chunks (read before any write; tid255 writes at end)
    float baseS = 0.f, baseQ = 0.f, baseP = 0.f;
    if (t_base != 0) { baseS = carryS[bg]; baseQ = carryQ[bg]; baseP = carryP[bg]; }

    float mv[TPT];
    float mk[TPT];
    float S = 0.f, Q = 0.f, P = 0.f;
    for (int i = 0; i < TPT; ++i) {
        const int t = t0 + i;
        const float v = m[((size_t)b * Ln + t) * Gn + g];
        const float k = mask[b * Ln + t] ? 1.f : 0.f;
        mv[i] = v;
        mk[i] = k;
        S += k * v;
        Q += k * v * v;
        P += k;
    }

    __shared__ float sS[256], sQ[256], sP[256];
    sS[tid] = S; sQ[tid] = Q; sP[tid] = P;
    __syncthreads();
    for (int off = 1; off < 256; off <<= 1) {
        float aS = 0.f, aQ = 0.f, aP = 0.f;
        if (tid >= off) { aS = sS[tid - off]; aQ = sQ[tid - off]; aP = sP[tid - off]; }
        __syncthreads();
        sS[tid] += aS; sQ[tid] += aQ; sP[tid] += aP;
        __syncthreads();
    }
    const float eS = baseS + (tid ? sS[tid - 1] : 0.f);
    const float eQ = baseQ + (tid ? sQ[tid - 1] : 0.f);
    const float eP = baseP + (tid ? sP[tid - 1] : 0.f);

    const float c0  = (float)prev_count[b];
    const float mu0 = prev_mean[bg];
    const float v0  = prev_var[bg];
    const float A0  = c0 * mu0;
    const float M2b = v0 * fmaxf(c0, 1.f) + c0 * mu0 * mu0;

    float rS = eS, rQ = eQ, rP = eP;
    for (int i = 0; i < TPT; ++i) {
        rS += mk[i] * mv[i];
        rQ += mk[i] * mv[i] * mv[i];
        rP += mk[i];
        const float c  = c0 + rP;
        const float cs = fmaxf(c, 1.f);
        const float mean = (A0 + rS) / cs;
        const float var  = (M2b + rQ - cs * mean * mean) / cs;
        const size_t idx = ((size_t)b * Ln + (t0 + i)) * Gn + g;
        mu[idx]   = mean;
        rstd[idx] = rsqrtf(var + EPS);
        if (t0 + i == Ln - 1) {          // last chunk only
            out_mean[bg] = mean;
            out_var[bg]  = var;
            if (g == 0) out_count[b] = c;
        }
    }
    if (tid == 255) {                    // inclusive total for this chunk
        carryS[bg] = rS; carryQ[bg] = rQ; carryP[bg] = rP;
    }
}

// ---------------------------------------------------------------------------
// P3: normalize + affine for one time-chunk (x re-read should hit L3).
// ---------------------------------------------------------------------------
__global__ __launch_bounds__(256) void k_norm(const float* __restrict__ x,
                                              const float* __restrict__ mu,
                                              const float* __restrict__ rstd,
                                              const float* __restrict__ w,
                                              const float* __restrict__ bias,
                                              float* __restrict__ y,
                                              int t_base) {
    const int idx = blockIdx.x;
    const int b = idx / CLn;
    const int tt = idx - b * CLn;
    const int row = b * Ln + t_base + tt;
    const int tid = threadIdx.x;
    const int g = tid >> 3;
    const size_t gi = (size_t)row * Gn + g;
    const float mean = mu[gi];
    const float rs   = rstd[gi];
    const float4* xr = reinterpret_cast<const float4*>(x + (size_t)row * Dn) + tid * 2;
    const float4* wr = reinterpret_cast<const float4*>(w) + tid * 2;
    const float4* br = reinterpret_cast<const float4*>(bias) + tid * 2;
    float4* yr = reinterpret_cast<float4*>(y + (size_t)row * Dn) + tid * 2;
#pragma unroll
    for (int i = 0; i < 2; ++i) {
        const float4 xv = xr[i];
        const float4 wv = wr[i];
        const float4 bv = br[i];
        float4 o;
        o.x = (xv.x - mean) * rs * wv.x + bv.x;
        o.y = (xv.y - mean) * rs * wv.y + bv.y;
        o.z = (xv.z - mean) * rs * wv.z + bv.z;
        o.w = (xv.w - mean) * rs * wv.w + bv.w;
        yr[i] = o;
    }
}

// ---------------------------------------------------------------------------
extern "C" void kernel_launch(void* const* d_in, const int* in_sizes, int n_in,
                              void* d_out, int out_size, void* d_ws, size_t ws_size,
                              hipStream_t stream) {
    (void)in_sizes; (void)n_in; (void)out_size; (void)ws_size;

    const float* x          = (const float*)d_in[0];
    const int*   mask       = (const int*)d_in[1];     // bool pushed as int32
    const int*   prev_count = (const int*)d_in[2];     // int pushed as int32
    const float* prev_mean  = (const float*)d_in[3];
    const float* prev_var   = (const float*)d_in[4];
    const float* weight     = (const float*)d_in[5];
    const float* bias       = (const float*)d_in[6];

    float* out = (float*)d_out;
    float* y         = out;                                   // B*L*D
    float* out_count = out + (size_t)Bn * Ln * Dn;            // B
    float* out_mean  = out_count + Bn;                        // B*G
    float* out_var   = out_mean + (size_t)Bn * Gn;            // B*G

    // workspace layout: m | mu | rstd (each B*L*G floats) | carries (3*256)
    const size_t nBLG = (size_t)Bn * Ln * Gn;
    float* m      = (float*)d_ws;
    float* mu     = m + nBLG;
    float* rstd   = mu + nBLG;
    float* carryS = rstd + nBLG;
    float* carryQ = carryS + Bn * Gn;
    float* carryP = carryQ + Bn * Gn;

    const int rows_per_chunk = Bn * CLn;  // 8192
    for (int c = 0; c < NCH; ++c) {
        const int t_base = c * CLn;
        k_group_means<<<rows_per_chunk, 256, 0, stream>>>(x, m, t_base);
        k_scan<<<Bn * Gn, 256, 0, stream>>>(m, mask, prev_count, prev_mean, prev_var,
                                            mu, rstd, carryS, carryQ, carryP,
                                            out_count, out_mean, out_var, t_base);
        k_norm<<<rows_per_chunk, 256, 0, stream>>>(x, mu, rstd, weight, bias, y, t_base);
    }
}